// Round 10
// baseline (213.090 us; speedup 1.0000x reference)
//
#include <hip/hip_runtime.h>

// Soft differentiable rasterizer, forward only. Two-kernel structure.
// R9 -> R10:
//  * raster: latency-bound (VALUBusy 66% at 28 iters). Pairwise unrolled
//    K-loop: lists padded to even length with dummy slot 128 (zero coef,
//    g=0), two slots' list-byte + scalar coef loads issue together, two
//    independent sigmoid-product chains interleave, serial composite,
//    exit check per pair, next pair's slot bytes prefetched.
//  * setup: cull-phase s_pq was b128 at 96 B lane stride (~16-way bank
//    conflicts); now SoA sQ[k][N]/sP[k][N], stride-1 lane reads.
//    s_list row stride 128->132 B so compaction writes spread banks.
// Design: 32x2 px tiles, joint gx-interval cull at CULL_U, coefficients via
// scalar cache (slot readfirstlane-uniform), packed-fp32 sigmoid product,
// front-to-back transmittance, wave exit at T < 2e-3.

#define HH 128
#define WW 128
#define NN 128
#define KK 12
#define STPB 1024
#define RTPB 256
#define STATE_SZ (NN * KK * 2 + NN) // 3200
#define CULL_U 15.0f
#define COEF_STRIDE 40              // floats per slot: A[12] B[12] C[12] gc[4]
#define NSLOT (NN + 1)              // +1 dummy slot (all-zero coef)
#define LISTP 132                   // padded LDS list row stride (bytes)

typedef float f2 __attribute__((ext_vector_type(2)));

__global__ __launch_bounds__(STPB) void setup_kernel(
    const float* __restrict__ traj,
    const float* __restrict__ colors,
    const float* __restrict__ alpha,
    const float* __restrict__ zval,
    const void*  __restrict__ csg_raw,
    float* __restrict__ g_coef,         // [T][129][40]
    int* __restrict__ g_cnt,            // [T][256]
    unsigned char* __restrict__ g_list) // [T][256][128]
{
    __shared__ __align__(16) float s_coef[NN][COEF_STRIDE];       // 20.5 KB
    __shared__ float sQ[KK][NN];                                  // 6.1 KB
    __shared__ float sP[KK][NN];                                  // 6.1 KB
    __shared__ float s_state[STATE_SZ];                           // 12.8 KB
    __shared__ float s_orient[NN];
    __shared__ float s_z[NN];
    __shared__ int   s_slot2prim[NN];
    __shared__ int   s_npos[NN], s_nneg[NN];
    __shared__ unsigned long long s_qbits[HH][4][2];              // 8 KB
    __shared__ unsigned char s_list[256][LISTP];                  // 33.8 KB
    __shared__ int s_cnt[256];
    __shared__ int s_mode;

    const int frame = blockIdx.x;
    const int tid   = threadIdx.x;
    const float* st = traj + (size_t)frame * STATE_SZ;

    // ---- stage + csg layout detect + counter init ----
    for (int i = tid; i < STATE_SZ; i += STPB) s_state[i] = st[i];
    if (tid < NN) { s_z[tid] = zval[tid]; s_npos[tid] = 0; s_nneg[tid] = 0; }
    if (tid == 0) {
        const unsigned char* b = (const unsigned char*)csg_raw;
        const unsigned int*  w = (const unsigned int*)csg_raw;
        int mode = 0; // int32
        bool words01 = true;
        for (int i = 0; i < 32; i++) if (w[i] > 1u) { words01 = false; break; }
        if (!words01) {
            bool bytes01 = true;
            for (int i = 0; i < 128; i++) if (b[i] > 1) { bytes01 = false; break; }
            mode = bytes01 ? 1 : 2;
        }
        s_mode = mode;
    }
    __syncthreads();

    // ---- per-prim: orient, g = alpha*sigmoid(alive), z-rank -> slot ----
    if (tid < NN) {
        const int n = tid;
        float area2 = 0.f;
        #pragma unroll
        for (int k = 0; k < KK; k++) {
            int k1 = (k + 1) % KK;
            float v0x = s_state[(n * KK + k)  * 2 + 0];
            float v0y = s_state[(n * KK + k)  * 2 + 1];
            float v1x = s_state[(n * KK + k1) * 2 + 0];
            float v1y = s_state[(n * KK + k1) * 2 + 1];
            area2 += v0x * v1y - v1x * v0y;
        }
        float orient = (area2 > 0.f) ? 1.f : ((area2 < 0.f) ? -1.f : 0.f);
        s_orient[n] = orient;

        float alive = s_state[NN * KK * 2 + n];
        float g = alpha[n] / (1.f + __expf(-alive));

        float zn = s_z[n];
        int rank = 0;
        for (int j = 0; j < NN; j++) {
            float zj = s_z[j];
            rank += (zj < zn || (zj == zn && j < n)) ? 1 : 0;
        }
        int slot = (NN - 1) - rank; // slot 0 = frontmost (largest z)
        s_slot2prim[slot] = n;

        int mode = s_mode;
        int sub;
        if (mode == 0)      sub = ((const int*)csg_raw)[n] != 0;
        else if (mode == 1) sub = ((const unsigned char*)csg_raw)[n] != 0;
        else                sub = ((const float*)csg_raw)[n] != 0.f;
        float cs = sub ? 0.f : 1.f;
        s_coef[slot][36] = g;
        s_coef[slot][37] = colors[n * 3 + 0] * cs;
        s_coef[slot][38] = colors[n * 3 + 1] * cs;
        s_coef[slot][39] = colors[n * 3 + 2] * cs;
    }
    __syncthreads();

    // ---- edge coefficients (slot-ordered SoA) ----
    const float QSCALE = 100.0f * 1.4426950408889634f;
    for (int idx = tid; idx < NN * KK; idx += STPB) {
        int slot = idx / KK;
        int k    = idx - slot * KK;
        int n    = s_slot2prim[slot];
        int k1   = (k + 1) % KK;
        float v0x = s_state[(n * KK + k)  * 2 + 0];
        float v0y = s_state[(n * KK + k)  * 2 + 1];
        float v1x = s_state[(n * KK + k1) * 2 + 0];
        float v1y = s_state[(n * KK + k1) * 2 + 1];
        float ex = v1x - v0x, ey = v1y - v0y;
        float q  = -s_orient[n] * QSCALE;
        s_coef[slot][0  + k] = q * ex;                      // A
        s_coef[slot][12 + k] = -q * ey;                     // B
        s_coef[slot][24 + k] = -q * (ex * v0y - ey * v0x);  // C
    }
    __syncthreads();

    // ---- line form per edge: x-constraint t(gy) = Q*gy + P, SoA ----
    // B>0: x <= t (+SLACK); B<0: x >= t (stored negated); B==0: inert entry.
    // Pos edges packed first (k < npos). Strided loop (R8 bug was a bare if).
    const float SLACK = 0.01f;
    for (int idx = tid; idx < NN * KK; idx += STPB) {
        int slot = idx / KK;
        int k    = idx - slot * KK;
        float A = s_coef[slot][k];
        float B = s_coef[slot][12 + k];
        float C = s_coef[slot][24 + k];
        float rcpB = __builtin_amdgcn_rcpf(B);
        float Praw = (CULL_U - C) * rcpB;
        float Qraw = -A * rcpB;
        if (B > 0.f) {
            int i = atomicAdd(&s_npos[slot], 1);
            sQ[i][slot] = Qraw; sP[i][slot] = Praw + SLACK;
        } else if (B < 0.f) {
            int i = atomicAdd(&s_nneg[slot], 1);
            sQ[(KK - 1) - i][slot] = -Qraw; sP[(KK - 1) - i][slot] = -Praw + SLACK;
        } else { // B == 0: conservatively no x-constraint
            int i = atomicAdd(&s_nneg[slot], 1);
            sQ[(KK - 1) - i][slot] = 0.f; sP[(KK - 1) - i][slot] = 1e30f;
        }
    }
    __syncthreads();

    // ---- joint interval cull; 4 x-quarter keep masks per row ----
    // lane = slot s (stride-1 LDS reads, conflict-free); wave row-uniform.
    const float GX_LO = 0.5f / WW;
    const float GX_HI = (WW - 0.5f) / WW;
    for (int j = 0; j < (HH * NN) / STPB; j++) {     // 16 iters
        int idx = j * STPB + tid;
        int r = idx >> 7, s = idx & (NN - 1);
        float gyr = (r + 0.5f) * (1.0f / HH);
        int npos = s_npos[s];
        float y1 = 1e30f, y2 = 1e30f;
        #pragma unroll
        for (int k = 0; k < KK; k++) {
            float t = fmaf(sQ[k][s], gyr, sP[k][s]);
            bool p = k < npos;
            y1 = fminf(y1, p ? t : 1e30f);
            y2 = fminf(y2, p ? 1e30f : t);
        }
        float xhi = fminf(y1, GX_HI);
        float xlo = fmaxf(-y2, GX_LO);
        bool ne = (xlo <= xhi);
        #pragma unroll
        for (int q = 0; q < 4; q++) {
            float qlo = (q * 32 + 0.5f) * (1.0f / WW);
            float qhi = (q * 32 + 31.5f) * (1.0f / WW);
            unsigned long long m = __ballot(ne && (xlo <= qhi) && (xhi >= qlo));
            if ((tid & 63) == 0) s_qbits[r][q][(s >= 64) ? 1 : 0] = m;
        }
    }
    __syncthreads();

    // ---- compaction: thread = tile (row-pair x x-quarter), slot-ascending;
    //      pad count to EVEN with dummy slot 128 (zero coef, g=0) ----
    if (tid < 256) {
        int rp = tid >> 2, q = tid & 3;
        unsigned long long b0 = s_qbits[2 * rp][q][0] | s_qbits[2 * rp + 1][q][0];
        unsigned long long b1 = s_qbits[2 * rp][q][1] | s_qbits[2 * rp + 1][q][1];
        int n = 0;
        while (b0) { int k = __builtin_ctzll(b0); b0 &= b0 - 1; s_list[tid][n++] = (unsigned char)k; }
        while (b1) { int k = __builtin_ctzll(b1); b1 &= b1 - 1; s_list[tid][n++] = (unsigned char)(64 + k); }
        if (n & 1) { s_list[tid][n] = (unsigned char)NN; n++; } // dummy
        s_cnt[tid] = n;
    }
    __syncthreads();

    // ---- copy out ----
    {
        float* dstc = g_coef + (size_t)frame * (NSLOT * COEF_STRIDE);
        const float* srcc = &s_coef[0][0];
        for (int i = tid; i < NN * COEF_STRIDE; i += STPB) dstc[i] = srcc[i];
        if (tid < COEF_STRIDE) dstc[NN * COEF_STRIDE + tid] = 0.f; // dummy slot
        if (tid < 256) g_cnt[frame * 256 + tid] = s_cnt[tid];
        unsigned int* dstl = (unsigned int*)(g_list + (size_t)frame * (256 * NN));
        for (int i = tid; i < 256 * (NN / 4); i += STPB) {
            int row = i >> 5, w = i & 31;
            dstl[i] = *(const unsigned int*)&s_list[row][w * 4];
        }
    }
}

struct F3 { float x, y, z; };

__global__ __launch_bounds__(RTPB) void raster_kernel(
    const float* __restrict__ g_coef,
    const int* __restrict__ g_cnt,
    const unsigned char* __restrict__ g_list,
    float* __restrict__ out)
{
    __shared__ unsigned char s_wlist[4][136];

    const int tid   = threadIdx.x;
    const int wv    = __builtin_amdgcn_readfirstlane(tid >> 6);
    const int lane  = tid & 63;
    const int frame = blockIdx.y;
    const int tile  = blockIdx.x * 4 + wv;  // 0..255
    const int rp    = tile >> 2;            // row pair
    const int q     = tile & 3;             // x quarter

    // stage this wave's survivor list into its private LDS strip
    const unsigned char* lst = g_list + ((size_t)frame * 256 + tile) * NN;
    if (lane < NN / 4) {
        ((unsigned int*)&s_wlist[wv][0])[lane] = ((const unsigned int*)lst)[lane];
    }
    const int cnt = g_cnt[frame * 256 + tile]; // uniform (even) -> s_load

    const int lx  = lane & 31, ly = lane >> 5;
    const int px  = q * 32 + lx;
    const int row = rp * 2 + ly;
    const float gy = (row + 0.5f) * (1.0f / HH);
    const float gx = (px  + 0.5f) * (1.0f / WW);
    const f2 gy2 = {gy, gy};
    const f2 gx2 = {gx, gx};
    const f2 lo2 = {-100.f, -100.f};

    const float* cfr = g_coef + (size_t)frame * (NSLOT * COEF_STRIDE);

    float Tt = 1.f, rr = 0.f, gg = 0.f, bb = 0.f;

    int sA = __builtin_amdgcn_readfirstlane((int)s_wlist[wv][0]);
    int sB = __builtin_amdgcn_readfirstlane((int)s_wlist[wv][1]);
    for (int i = 0; i < cnt; i += 2) {
        // prefetch next pair's slot bytes (pad region: read-only, never used)
        int sC = __builtin_amdgcn_readfirstlane((int)s_wlist[wv][i + 2]);
        int sD = __builtin_amdgcn_readfirstlane((int)s_wlist[wv][i + 3]);

        const float* cfA = cfr + sA * COEF_STRIDE; // uniform -> scalar loads
        const float* cfB = cfr + sB * COEF_STRIDE; // both issue up front

        f2 qA = {1.f, 1.f}, qB = {1.f, 1.f};
        #pragma unroll
        for (int j = 0; j < 6; j++) {
            f2 uA = __builtin_elementwise_fma(((const f2*)(cfA + 12))[j], gx2,
                      __builtin_elementwise_fma(((const f2*)cfA)[j], gy2,
                                                ((const f2*)(cfA + 24))[j]));
            f2 uB = __builtin_elementwise_fma(((const f2*)(cfB + 12))[j], gx2,
                      __builtin_elementwise_fma(((const f2*)cfB)[j], gy2,
                                                ((const f2*)(cfB + 24))[j]));
            uA = __builtin_elementwise_max(uA, lo2); // exp2 underflow guard
            uB = __builtin_elementwise_max(uB, lo2);
            f2 eA, eB;
            eA.x = __builtin_amdgcn_exp2f(uA.x);
            eA.y = __builtin_amdgcn_exp2f(uA.y);
            eB.x = __builtin_amdgcn_exp2f(uB.x);
            eB.y = __builtin_amdgcn_exp2f(uB.y);
            qA = __builtin_elementwise_fma(qA, eA, qA); // q *= 1 + 2^u
            qB = __builtin_elementwise_fma(qB, eB, qB);
        }
        float covA = __builtin_amdgcn_rcpf(qA.x * qA.y);
        float covB = __builtin_amdgcn_rcpf(qB.x * qB.y);

        float aA = covA * cfA[36];
        float wA = aA * Tt;
        rr = fmaf(wA, cfA[37], rr);
        gg = fmaf(wA, cfA[38], gg);
        bb = fmaf(wA, cfA[39], bb);
        Tt = fmaf(-aA, Tt, Tt);

        float aB = covB * cfB[36];
        float wB = aB * Tt;
        rr = fmaf(wB, cfB[37], rr);
        gg = fmaf(wB, cfB[38], gg);
        bb = fmaf(wB, cfB[39], bb);
        Tt = fmaf(-aB, Tt, Tt);

        if (!__any(Tt > 2e-3f)) break;   // residual <= T < 2e-3
        sA = sC; sB = sD;
    }

    size_t o = ((size_t)frame * (HH * WW) + (size_t)row * WW + px) * 3;
    *(F3*)(out + o) = F3{rr, gg, bb};    // coalesced dwordx3 per row segment
}

extern "C" void kernel_launch(void* const* d_in, const int* in_sizes, int n_in,
                              void* d_out, int out_size, void* d_ws, size_t ws_size,
                              hipStream_t stream) {
    const float* traj   = (const float*)d_in[0];
    const float* colors = (const float*)d_in[1];
    const float* alpha  = (const float*)d_in[2];
    const float* zval   = (const float*)d_in[3];
    const void*  csg    = d_in[4];
    float* out = (float*)d_out;

    const int T = in_sizes[0] / STATE_SZ; // 192

    size_t coef_sz = (size_t)T * NSLOT * COEF_STRIDE * sizeof(float); // 3.96 MB
    size_t cnt_sz  = (size_t)T * 256 * sizeof(int);                   // 0.20 MB
    float* g_coef = (float*)d_ws;
    int*   g_cnt  = (int*)((char*)d_ws + coef_sz);
    unsigned char* g_list = (unsigned char*)d_ws + coef_sz + cnt_sz;  // 6.29 MB

    setup_kernel<<<T, STPB, 0, stream>>>(traj, colors, alpha, zval, csg,
                                         g_coef, g_cnt, g_list);
    dim3 grid(256 / 4, T); // 64 x 192, wave = one 32x2 tile
    raster_kernel<<<grid, RTPB, 0, stream>>>(g_coef, g_cnt, g_list, out);
}